// Round 1
// baseline (1752.537 us; speedup 1.0000x reference)
//
#include <hip/hip_runtime.h>
#include <math.h>

#define B_ 8192
#define IN_ 8000
#define C_ 16
#define S_ 500
#define O_ 64
#define F_ 1024
#define E_ 8
#define D_ 512
#define T_ 2
#define OUTW 34
#define EPS_ 1e-5f

__device__ __forceinline__ float swishf(float x) {
    return x / (1.0f + __expf(-x));
}

// -------------------- SplitLinear: h0[b, c*64+o] = sum_s x[b,c*500+s]*w0[c,o,s] + b0 --------------------
// grid (B/64, C), block 256 (16x16), 4x4 per thread
__global__ __launch_bounds__(256) void k_split(const float* __restrict__ x,
                                               const float* __restrict__ w0,
                                               const float* __restrict__ b0,
                                               float* __restrict__ h0) {
    const int KT = 20;
    __shared__ __align__(16) float xs[KT][68];  // [k][b], pad to 68 for 16B row alignment
    __shared__ __align__(16) float ws[KT][68];  // [k][o]
    int bt = blockIdx.x;
    int c  = blockIdx.y;
    int tid = threadIdx.x;
    int tx = tid & 15, ty = tid >> 4;
    int brow0 = bt * 64;
    const float* xp = x + (size_t)brow0 * IN_ + c * S_;
    const float* wp = w0 + (size_t)c * O_ * S_;
    float acc[4][4];
#pragma unroll
    for (int i = 0; i < 4; i++)
#pragma unroll
        for (int j = 0; j < 4; j++) acc[i][j] = 0.f;

    for (int k0 = 0; k0 < S_; k0 += KT) {
#pragma unroll
        for (int i = 0; i < 5; i++) {
            int li = tid + i * 256;          // 64*20 = 1280 elements
            int bi = li / KT, k = li % KT;   // consecutive tid -> consecutive k (coalesced)
            xs[k][bi] = xp[(size_t)bi * IN_ + k0 + k];
            ws[k][bi] = wp[bi * S_ + k0 + k];
        }
        __syncthreads();
#pragma unroll
        for (int k = 0; k < KT; k++) {
            float a0 = xs[k][ty * 4 + 0], a1 = xs[k][ty * 4 + 1];
            float a2 = xs[k][ty * 4 + 2], a3 = xs[k][ty * 4 + 3];
            float w0v = ws[k][tx * 4 + 0], w1v = ws[k][tx * 4 + 1];
            float w2v = ws[k][tx * 4 + 2], w3v = ws[k][tx * 4 + 3];
            acc[0][0] += a0 * w0v; acc[0][1] += a0 * w1v; acc[0][2] += a0 * w2v; acc[0][3] += a0 * w3v;
            acc[1][0] += a1 * w0v; acc[1][1] += a1 * w1v; acc[1][2] += a1 * w2v; acc[1][3] += a1 * w3v;
            acc[2][0] += a2 * w0v; acc[2][1] += a2 * w1v; acc[2][2] += a2 * w2v; acc[2][3] += a2 * w3v;
            acc[3][0] += a3 * w0v; acc[3][1] += a3 * w1v; acc[3][2] += a3 * w2v; acc[3][3] += a3 * w3v;
        }
        __syncthreads();
    }
    int ocol0 = c * O_;
#pragma unroll
    for (int i = 0; i < 4; i++) {
#pragma unroll
        for (int j = 0; j < 4; j++) {
            int oc = ocol0 + tx * 4 + j;
            h0[(size_t)(brow0 + ty * 4 + i) * F_ + oc] = acc[i][j] + b0[oc];
        }
    }
}

// -------------------- Column stats phase A: partial sum/sumsq over row blocks --------------------
// grid (N/64, YS, Z), block 256 as (64 n, 4 b). psum layout [(z*YS+y)*N + n]
__global__ __launch_bounds__(256) void k_stats_a(const float* __restrict__ mat,
                                                 unsigned long long slab, int N,
                                                 float* __restrict__ psum,
                                                 float* __restrict__ psq) {
    int tx = threadIdx.x & 63, ty = threadIdx.x >> 6;
    int n = blockIdx.x * 64 + tx;
    int YS = gridDim.y;
    const float* m = mat + (size_t)blockIdx.z * slab;
    int rows = B_ / YS;
    int r0 = blockIdx.y * rows;
    float s = 0.f, q = 0.f;
    for (int r = r0 + ty; r < r0 + rows; r += 4) {
        float v = m[(size_t)r * N + n];
        s += v; q += v * v;
    }
    __shared__ float a1[4][64], a2[4][64];
    a1[ty][tx] = s; a2[ty][tx] = q;
    __syncthreads();
    if (ty == 0) {
        s = a1[0][tx] + a1[1][tx] + a1[2][tx] + a1[3][tx];
        q = a2[0][tx] + a2[1][tx] + a2[2][tx] + a2[3][tx];
        size_t idx = ((size_t)(blockIdx.z * YS + blockIdx.y)) * N + n;
        psum[idx] = s; psq[idx] = q;
    }
}

// -------------------- Column stats phase B: finalize to scale/shift --------------------
// grid (N/64, 1, Z), block 64.  scale = g*rsqrt(var+eps); shift = beta - mean*scale
__global__ __launch_bounds__(64) void k_stats_b(const float* __restrict__ psum,
                                                const float* __restrict__ psq,
                                                int N, int YS,
                                                const float* __restrict__ g,
                                                const float* __restrict__ beta,
                                                unsigned long long gslab,
                                                float* __restrict__ scale,
                                                float* __restrict__ shift,
                                                unsigned long long oslab) {
    int n = blockIdx.x * 64 + threadIdx.x;
    int z = blockIdx.z;
    float s = 0.f, q = 0.f;
    for (int y = 0; y < YS; y++) {
        size_t idx = ((size_t)(z * YS + y)) * N + n;
        s += psum[idx]; q += psq[idx];
    }
    float mean = s * (1.0f / B_);
    float var = q * (1.0f / B_) - mean * mean;
    float sc = g[z * gslab + n] * rsqrtf(var + EPS_);
    scale[z * oslab + n] = sc;
    shift[z * oslab + n] = beta[z * gslab + n] - mean * sc;
}

// -------------------- BN+swish h0 in place + per-task gate softmax --------------------
// grid B, block 256
__global__ __launch_bounds__(256) void k_bnswish_gates(float* __restrict__ h0,
                                                       const float* __restrict__ scale,
                                                       const float* __restrict__ shift,
                                                       const float* __restrict__ gate_w,
                                                       const float* __restrict__ gate_b,
                                                       float* __restrict__ gates) {
    int b = blockIdx.x, tid = threadIdx.x;
    float part[16];
#pragma unroll
    for (int i = 0; i < 16; i++) part[i] = 0.f;
    float* row = h0 + (size_t)b * F_;
#pragma unroll
    for (int it = 0; it < 4; it++) {
        int f = tid + it * 256;
        float v = row[f];
        float hv = scale[f] * v + shift[f];
        float sw = swishf(hv);
        row[f] = sw;
        const float* gw0 = gate_w + (size_t)f * E_;
        const float* gw1 = gate_w + (size_t)(F_ * E_) + (size_t)f * E_;
#pragma unroll
        for (int e = 0; e < E_; e++) part[e] += sw * gw0[e];
#pragma unroll
        for (int e = 0; e < E_; e++) part[8 + e] += sw * gw1[e];
    }
#pragma unroll
    for (int i = 0; i < 16; i++) {
        float v = part[i];
        for (int off = 32; off > 0; off >>= 1) v += __shfl_down(v, off, 64);
        part[i] = v;
    }
    __shared__ float red[4][16];
    __shared__ float gfin[16];
    int wave = tid >> 6, lane = tid & 63;
    if (lane == 0) {
#pragma unroll
        for (int i = 0; i < 16; i++) red[wave][i] = part[i];
    }
    __syncthreads();
    if (tid < 16) {
        float v = red[0][tid] + red[1][tid] + red[2][tid] + red[3][tid];
        int t = tid >> 3, e = tid & 7;
        gfin[tid] = v + gate_b[t * E_ + e];
    }
    __syncthreads();
    if (tid < 2) {
        float mx = -1e30f;
#pragma unroll
        for (int e = 0; e < 8; e++) mx = fmaxf(mx, gfin[tid * 8 + e]);
        float ex[8], sum = 0.f;
#pragma unroll
        for (int e = 0; e < 8; e++) { ex[e] = __expf(gfin[tid * 8 + e] - mx); sum += ex[e]; }
        float inv = 1.0f / sum;
#pragma unroll
        for (int e = 0; e < 8; e++)
            gates[(size_t)tid * (B_ * E_) + (size_t)b * E_ + e] = ex[e] * inv;
    }
}

// -------------------- Generic NN SGEMM: C[r,n] = sum_k A[r,k] * W[k,n] --------------------
// A: [B_,K] lda=K, slab per grid.z; W: [K,N] N = gridDim.y*64, slab per z; C: row stride ldc, slab per z
// grid (B/64, N/64, Z), block 256, 64x64 tile, 4x4 per thread
__global__ __launch_bounds__(256) void k_gemm_nn(const float* __restrict__ A,
                                                 unsigned long long aslab,
                                                 const float* __restrict__ W,
                                                 unsigned long long wslab,
                                                 float* __restrict__ C,
                                                 unsigned long long cslab,
                                                 int K, int ldc) {
    const int KT = 32;
    __shared__ __align__(16) float As[KT][68];
    __shared__ __align__(16) float Ws[KT][68];
    int g = blockIdx.z;
    A += (size_t)g * aslab;
    W += (size_t)g * wslab;
    C += (size_t)g * cslab;
    int row0 = blockIdx.x * 64, col0 = blockIdx.y * 64;
    int N = gridDim.y * 64;
    int tid = threadIdx.x;
    int tx = tid & 15, ty = tid >> 4;
    float acc[4][4];
#pragma unroll
    for (int i = 0; i < 4; i++)
#pragma unroll
        for (int j = 0; j < 4; j++) acc[i][j] = 0.f;

    for (int k0 = 0; k0 < K; k0 += KT) {
#pragma unroll
        for (int i = 0; i < 8; i++) {
            int li = tid + i * 256;
            int r = li >> 5, k = li & 31;
            As[k][r] = A[(size_t)(row0 + r) * K + k0 + k];
        }
#pragma unroll
        for (int i = 0; i < 8; i++) {
            int li = tid + i * 256;
            int k = li >> 6, n = li & 63;
            Ws[k][n] = W[(size_t)(k0 + k) * N + col0 + n];
        }
        __syncthreads();
#pragma unroll
        for (int k = 0; k < KT; k++) {
            float a0 = As[k][ty * 4 + 0], a1 = As[k][ty * 4 + 1];
            float a2 = As[k][ty * 4 + 2], a3 = As[k][ty * 4 + 3];
            float b0v = Ws[k][tx * 4 + 0], b1v = Ws[k][tx * 4 + 1];
            float b2v = Ws[k][tx * 4 + 2], b3v = Ws[k][tx * 4 + 3];
            acc[0][0] += a0 * b0v; acc[0][1] += a0 * b1v; acc[0][2] += a0 * b2v; acc[0][3] += a0 * b3v;
            acc[1][0] += a1 * b0v; acc[1][1] += a1 * b1v; acc[1][2] += a1 * b2v; acc[1][3] += a1 * b3v;
            acc[2][0] += a2 * b0v; acc[2][1] += a2 * b1v; acc[2][2] += a2 * b2v; acc[2][3] += a2 * b3v;
            acc[3][0] += a3 * b0v; acc[3][1] += a3 * b1v; acc[3][2] += a3 * b2v; acc[3][3] += a3 * b3v;
        }
        __syncthreads();
    }
#pragma unroll
    for (int i = 0; i < 4; i++) {
#pragma unroll
        for (int j = 0; j < 4; j++) {
            C[(size_t)(row0 + ty * 4 + i) * ldc + col0 + tx * 4 + j] = acc[i][j];
        }
    }
}

// -------------------- expert BN+swish + gate-weighted mix over experts --------------------
// grid B, block 512 (d).  mix[t,b,d] = sum_e gates[t,b,e]*swish(bn(eh[b,e,d]))
__global__ __launch_bounds__(512) void k_mix(const float* __restrict__ eh,
                                             const float* __restrict__ scale,
                                             const float* __restrict__ shift,
                                             const float* __restrict__ gates,
                                             float* __restrict__ mix) {
    int b = blockIdx.x, d = threadIdx.x;
    __shared__ float gl[2][8];
    if (threadIdx.x < 16)
        gl[threadIdx.x >> 3][threadIdx.x & 7] =
            gates[(size_t)(threadIdx.x >> 3) * (B_ * E_) + (size_t)b * E_ + (threadIdx.x & 7)];
    __syncthreads();
    float a0 = 0.f, a1 = 0.f;
#pragma unroll
    for (int e = 0; e < E_; e++) {
        int n = e * D_ + d;
        float v = eh[(size_t)b * (E_ * D_) + n];
        float hv = scale[n] * v + shift[n];
        float sw = swishf(hv);
        a0 += gl[0][e] * sw;
        a1 += gl[1][e] * sw;
    }
    mix[(size_t)b * D_ + d] = a0;
    mix[(size_t)(B_ * D_) + (size_t)b * D_ + d] = a1;
}

// -------------------- task BN+swish + final heads --------------------
// grid B, block 64. out[b,0:32] = swish(bn(th0)) @ fwa + fba ; out[b,32:34] = swish(bn(th1)) @ fwb + fbb
__global__ __launch_bounds__(64) void k_final(const float* __restrict__ th,
                                              const float* __restrict__ scale,
                                              const float* __restrict__ shift,
                                              const float* __restrict__ fwa,
                                              const float* __restrict__ fba,
                                              const float* __restrict__ fwb,
                                              const float* __restrict__ fbb,
                                              float* __restrict__ out) {
    __shared__ float t0[D_], t1[D_];
    int b = blockIdx.x, tid = threadIdx.x;
    for (int i = tid; i < D_; i += 64) {
        float v0 = th[(size_t)b * D_ + i];
        t0[i] = swishf(scale[i] * v0 + shift[i]);
        float v1 = th[(size_t)(B_ * D_) + (size_t)b * D_ + i];
        t1[i] = swishf(scale[D_ + i] * v1 + shift[D_ + i]);
    }
    __syncthreads();
    if (tid < 32) {
        float acc = fba[tid];
        for (int d = 0; d < D_; d++) acc += t0[d] * fwa[d * 32 + tid];
        out[(size_t)b * OUTW + tid] = acc;
    } else if (tid < 34) {
        int j = tid - 32;
        float acc = fbb[j];
        for (int d = 0; d < D_; d++) acc += t1[d] * fwb[d * 2 + j];
        out[(size_t)b * OUTW + tid] = acc;
    }
}

extern "C" void kernel_launch(void* const* d_in, const int* in_sizes, int n_in,
                              void* d_out, int out_size, void* d_ws, size_t ws_size,
                              hipStream_t stream) {
    const float* x        = (const float*)d_in[0];
    const float* w0       = (const float*)d_in[1];
    const float* b0       = (const float*)d_in[2];
    const float* bn0_g    = (const float*)d_in[3];
    const float* bn0_b    = (const float*)d_in[4];
    const float* gate_w   = (const float*)d_in[5];
    const float* gate_b   = (const float*)d_in[6];
    const float* exp_w    = (const float*)d_in[7];
    const float* exp_bn_g = (const float*)d_in[8];
    const float* exp_bn_b = (const float*)d_in[9];
    const float* task_w   = (const float*)d_in[10];
    const float* task_bn_g= (const float*)d_in[11];
    const float* task_bn_b= (const float*)d_in[12];
    const float* fwa      = (const float*)d_in[13];
    const float* fba      = (const float*)d_in[14];
    const float* fwb      = (const float*)d_in[15];
    const float* fbb      = (const float*)d_in[16];
    float* out = (float*)d_out;

    // workspace layout (floats); mix aliases h0, th aliases eh (lifetimes disjoint)
    float* ws    = (float*)d_ws;
    float* eh    = ws;                        // B*E*D = 33,554,432
    float* h0    = ws + 33554432;             // B*F   =  8,388,608
    float* th    = eh;                        // T*B*D =  8,388,608 (fits)
    float* mixb  = h0;                        // T*B*D =  8,388,608 (exact fit)
    float* gates = ws + 41943040;             // T*B*E =    131,072
    float* sc0   = ws + 42074112;             // 1024
    float* sh0   = sc0 + 1024;                // 1024
    float* scE   = sh0 + 1024;                // 4096
    float* shE   = scE + 4096;                // 4096
    float* scT   = shE + 4096;                // 1024
    float* shT   = scT + 1024;                // 1024
    float* psum  = shT + 1024;                // 131072
    float* psq   = psum + 131072;             // 131072
    // total ~162 MiB

    // 1) split linear -> h0 raw
    k_split<<<dim3(128, 16), 256, 0, stream>>>(x, w0, b0, h0);
    // 2) BN0 stats
    k_stats_a<<<dim3(16, 32, 1), 256, 0, stream>>>(h0, 0ull, F_, psum, psq);
    k_stats_b<<<dim3(16, 1, 1), 64, 0, stream>>>(psum, psq, F_, 32, bn0_g, bn0_b, 0ull, sc0, sh0, 0ull);
    // 3) BN0 apply + swish in place + gate softmax
    k_bnswish_gates<<<dim3(B_), 256, 0, stream>>>(h0, sc0, sh0, gate_w, gate_b, gates);
    // 4) expert GEMM: eh[b, e*512+d]
    k_gemm_nn<<<dim3(128, 8, 8), 256, 0, stream>>>(h0, 0ull, exp_w,
                                                   (unsigned long long)(F_ * D_), eh,
                                                   512ull, F_, E_ * D_);
    // 5) expert BN stats
    k_stats_a<<<dim3(64, 32, 1), 256, 0, stream>>>(eh, 0ull, E_ * D_, psum, psq);
    k_stats_b<<<dim3(64, 1, 1), 64, 0, stream>>>(psum, psq, E_ * D_, 32, exp_bn_g, exp_bn_b, 0ull, scE, shE, 0ull);
    // 6) expert BN apply + swish + gate mix -> mix[t,b,d] (aliases h0)
    k_mix<<<dim3(B_), 512, 0, stream>>>(eh, scE, shE, gates, mixb);
    // 7) task GEMM: th[t,b,k] (aliases eh)
    k_gemm_nn<<<dim3(128, 8, 2), 256, 0, stream>>>(mixb, (unsigned long long)(B_ * D_),
                                                   task_w, (unsigned long long)(D_ * D_),
                                                   th, (unsigned long long)(B_ * D_), D_, D_);
    // 8) task BN stats (per task slab)
    k_stats_a<<<dim3(8, 32, 2), 256, 0, stream>>>(th, (unsigned long long)(B_ * D_), D_, psum, psq);
    k_stats_b<<<dim3(8, 1, 2), 64, 0, stream>>>(psum, psq, D_, 32, task_bn_g, task_bn_b, 512ull, scT, shT, 512ull);
    // 9) task BN apply + swish + final heads -> out [B, 34]
    k_final<<<dim3(B_), 64, 0, stream>>>(th, scT, shT, fwa, fba, fwb, fbb, out);
}

// Round 2
// 832.392 us; speedup vs baseline: 2.1054x; 2.1054x over previous
//
#include <hip/hip_runtime.h>
#include <math.h>

#define B_ 8192
#define IN_ 8000
#define C_ 16
#define S_ 500
#define O_ 64
#define F_ 1024
#define E_ 8
#define D_ 512
#define T_ 2
#define OUTW 34
#define EPS_ 1e-5f

typedef __attribute__((ext_vector_type(8))) short bf16x8;
typedef __attribute__((ext_vector_type(4))) float f32x4;

__device__ __forceinline__ float swishf(float x) {
    return x / (1.0f + __expf(-x));
}

// round-to-nearest-even f32 -> bf16 bits
__device__ __forceinline__ unsigned short f2bf(float f) {
    union { float f; unsigned u; } c;
    c.f = f;
    unsigned r = c.u + 0x7fffu + ((c.u >> 16) & 1u);
    return (unsigned short)(r >> 16);
}

// async global->LDS, 16B per lane; LDS dest must be wave-uniform base (+lane*16 implicit)
__device__ __forceinline__ void gld16(const void* g, void* l) {
    __builtin_amdgcn_global_load_lds(
        (const __attribute__((address_space(1))) void*)g,
        (__attribute__((address_space(3))) void*)l, 16, 0, 0);
}

// -------------------- SplitLinear: h0[b, c*64+o] = sum_s x[b,c*500+s]*w0[c,o,s] + b0 --------------------
__global__ __launch_bounds__(256) void k_split(const float* __restrict__ x,
                                               const float* __restrict__ w0,
                                               const float* __restrict__ b0,
                                               float* __restrict__ h0) {
    const int KT = 20;
    __shared__ __align__(16) float xs[KT][68];
    __shared__ __align__(16) float ws[KT][68];
    int bt = blockIdx.x;
    int c  = blockIdx.y;
    int tid = threadIdx.x;
    int tx = tid & 15, ty = tid >> 4;
    int brow0 = bt * 64;
    const float* xp = x + (size_t)brow0 * IN_ + c * S_;
    const float* wp = w0 + (size_t)c * O_ * S_;
    float acc[4][4];
#pragma unroll
    for (int i = 0; i < 4; i++)
#pragma unroll
        for (int j = 0; j < 4; j++) acc[i][j] = 0.f;

    for (int k0 = 0; k0 < S_; k0 += KT) {
#pragma unroll
        for (int i = 0; i < 5; i++) {
            int li = tid + i * 256;
            int bi = li / KT, k = li % KT;
            xs[k][bi] = xp[(size_t)bi * IN_ + k0 + k];
            ws[k][bi] = wp[bi * S_ + k0 + k];
        }
        __syncthreads();
#pragma unroll
        for (int k = 0; k < KT; k++) {
            float a0 = xs[k][ty * 4 + 0], a1 = xs[k][ty * 4 + 1];
            float a2 = xs[k][ty * 4 + 2], a3 = xs[k][ty * 4 + 3];
            float w0v = ws[k][tx * 4 + 0], w1v = ws[k][tx * 4 + 1];
            float w2v = ws[k][tx * 4 + 2], w3v = ws[k][tx * 4 + 3];
            acc[0][0] += a0 * w0v; acc[0][1] += a0 * w1v; acc[0][2] += a0 * w2v; acc[0][3] += a0 * w3v;
            acc[1][0] += a1 * w0v; acc[1][1] += a1 * w1v; acc[1][2] += a1 * w2v; acc[1][3] += a1 * w3v;
            acc[2][0] += a2 * w0v; acc[2][1] += a2 * w1v; acc[2][2] += a2 * w2v; acc[2][3] += a2 * w3v;
            acc[3][0] += a3 * w0v; acc[3][1] += a3 * w1v; acc[3][2] += a3 * w2v; acc[3][3] += a3 * w3v;
        }
        __syncthreads();
    }
    int ocol0 = c * O_;
#pragma unroll
    for (int i = 0; i < 4; i++) {
#pragma unroll
        for (int j = 0; j < 4; j++) {
            int oc = ocol0 + tx * 4 + j;
            h0[(size_t)(brow0 + ty * 4 + i) * F_ + oc] = acc[i][j] + b0[oc];
        }
    }
}

// -------------------- Column stats phase A --------------------
__global__ __launch_bounds__(256) void k_stats_a(const float* __restrict__ mat,
                                                 unsigned long long slab, int N,
                                                 float* __restrict__ psum,
                                                 float* __restrict__ psq) {
    int tx = threadIdx.x & 63, ty = threadIdx.x >> 6;
    int n = blockIdx.x * 64 + tx;
    int YS = gridDim.y;
    const float* m = mat + (size_t)blockIdx.z * slab;
    int rows = B_ / YS;
    int r0 = blockIdx.y * rows;
    float s = 0.f, q = 0.f;
    for (int r = r0 + ty; r < r0 + rows; r += 4) {
        float v = m[(size_t)r * N + n];
        s += v; q += v * v;
    }
    __shared__ float a1[4][64], a2[4][64];
    a1[ty][tx] = s; a2[ty][tx] = q;
    __syncthreads();
    if (ty == 0) {
        s = a1[0][tx] + a1[1][tx] + a1[2][tx] + a1[3][tx];
        q = a2[0][tx] + a2[1][tx] + a2[2][tx] + a2[3][tx];
        size_t idx = ((size_t)(blockIdx.z * YS + blockIdx.y)) * N + n;
        psum[idx] = s; psq[idx] = q;
    }
}

// -------------------- Column stats phase B --------------------
__global__ __launch_bounds__(64) void k_stats_b(const float* __restrict__ psum,
                                                const float* __restrict__ psq,
                                                int N, int YS,
                                                const float* __restrict__ g,
                                                const float* __restrict__ beta,
                                                unsigned long long gslab,
                                                float* __restrict__ scale,
                                                float* __restrict__ shift,
                                                unsigned long long oslab) {
    int n = blockIdx.x * 64 + threadIdx.x;
    int z = blockIdx.z;
    float s = 0.f, q = 0.f;
    for (int y = 0; y < YS; y++) {
        size_t idx = ((size_t)(z * YS + y)) * N + n;
        s += psum[idx]; q += psq[idx];
    }
    float mean = s * (1.0f / B_);
    float var = q * (1.0f / B_) - mean * mean;
    float sc = g[z * gslab + n] * rsqrtf(var + EPS_);
    scale[z * oslab + n] = sc;
    shift[z * oslab + n] = beta[z * gslab + n] - mean * sc;
}

// -------------------- transpose-convert: in [Z][K][N] f32 -> out [Z][N][K] bf16 --------------------
// grid (K/32, N/32, Z), block 256
__global__ __launch_bounds__(256) void k_wt(const float* __restrict__ in,
                                            unsigned short* __restrict__ out,
                                            int K, int N) {
    __shared__ float t[32][33];
    int k0 = blockIdx.x * 32, n0 = blockIdx.y * 32, z = blockIdx.z;
    const float* ip = in + (size_t)z * K * N;
    unsigned short* op = out + (size_t)z * N * K;
    int tn = threadIdx.x & 31, tk = threadIdx.x >> 5;
#pragma unroll
    for (int p = 0; p < 4; p++) {
        int k = tk + p * 8;
        t[k][tn] = ip[(size_t)(k0 + k) * N + n0 + tn];
    }
    __syncthreads();
    int tk2 = threadIdx.x & 31, tn2 = threadIdx.x >> 5;
#pragma unroll
    for (int p = 0; p < 4; p++) {
        int n = tn2 + p * 8;
        op[(size_t)(n0 + n) * K + k0 + tk2] = f2bf(t[tk2][n]);
    }
}

// -------------------- BN+swish -> h0bf (bf16) + per-task gate softmax --------------------
__global__ __launch_bounds__(256) void k_bnswish_gates(const float* __restrict__ h0,
                                                       const float* __restrict__ scale,
                                                       const float* __restrict__ shift,
                                                       const float* __restrict__ gate_w,
                                                       const float* __restrict__ gate_b,
                                                       unsigned short* __restrict__ h0bf,
                                                       float* __restrict__ gates) {
    int b = blockIdx.x, tid = threadIdx.x;
    float part[16];
#pragma unroll
    for (int i = 0; i < 16; i++) part[i] = 0.f;
    const float* row = h0 + (size_t)b * F_;
    unsigned short* ob = h0bf + (size_t)b * F_;
#pragma unroll
    for (int it = 0; it < 4; it++) {
        int f = tid + it * 256;
        float v = row[f];
        float hv = scale[f] * v + shift[f];
        float sw = swishf(hv);
        ob[f] = f2bf(sw);
        const float* gw0 = gate_w + (size_t)f * E_;
        const float* gw1 = gate_w + (size_t)(F_ * E_) + (size_t)f * E_;
#pragma unroll
        for (int e = 0; e < E_; e++) part[e] += sw * gw0[e];
#pragma unroll
        for (int e = 0; e < E_; e++) part[8 + e] += sw * gw1[e];
    }
#pragma unroll
    for (int i = 0; i < 16; i++) {
        float v = part[i];
        for (int off = 32; off > 0; off >>= 1) v += __shfl_down(v, off, 64);
        part[i] = v;
    }
    __shared__ float red[4][16];
    __shared__ float gfin[16];
    int wave = tid >> 6, lane = tid & 63;
    if (lane == 0) {
#pragma unroll
        for (int i = 0; i < 16; i++) red[wave][i] = part[i];
    }
    __syncthreads();
    if (tid < 16) {
        float v = red[0][tid] + red[1][tid] + red[2][tid] + red[3][tid];
        int t = tid >> 3, e = tid & 7;
        gfin[tid] = v + gate_b[t * E_ + e];
    }
    __syncthreads();
    if (tid < 2) {
        float mx = -1e30f;
#pragma unroll
        for (int e = 0; e < 8; e++) mx = fmaxf(mx, gfin[tid * 8 + e]);
        float ex[8], sum = 0.f;
#pragma unroll
        for (int e = 0; e < 8; e++) { ex[e] = __expf(gfin[tid * 8 + e] - mx); sum += ex[e]; }
        float inv = 1.0f / sum;
#pragma unroll
        for (int e = 0; e < 8; e++)
            gates[(size_t)tid * (B_ * E_) + (size_t)b * E_ + e] = ex[e] * inv;
    }
}

// -------------------- bf16 MFMA GEMM: C[r,n] = sum_k A[r,k]*Wt[n,k] --------------------
// A: [M][K] bf16 k-contig; Wt: [N][K] bf16 k-contig; C: [M][N] f32. 128x128 tile, BK=32.
// grid (M/128, N/128, Z), block 256 (4 waves, 2x2 of 64x64 wave tiles)
__global__ __launch_bounds__(256) void k_gemm_bf16(const unsigned short* __restrict__ A,
                                                   unsigned long long aslab,
                                                   const unsigned short* __restrict__ Wt,
                                                   unsigned long long wslab,
                                                   float* __restrict__ C,
                                                   unsigned long long cslab, int K) {
    __shared__ __align__(16) unsigned short As[128 * 32];
    __shared__ __align__(16) unsigned short Ws[128 * 32];
    int z = blockIdx.z;
    A  += (size_t)z * aslab;
    Wt += (size_t)z * wslab;
    C  += (size_t)z * cslab;
    const int N = gridDim.y * 128;
    int row0 = blockIdx.x * 128, col0 = blockIdx.y * 128;
    int tid = threadIdx.x;
    int w = tid >> 6, lane = tid & 63;
    int l15 = lane & 15, quad = lane >> 4;

    // staging: each wave stages 32 A-rows and 32 Wt-rows (2 issues of 16 rows each)
    const unsigned short* ga0 = A  + (size_t)(row0 + w * 32 + (lane >> 2)) * K + (lane & 3) * 8;
    const unsigned short* ga1 = ga0 + 16 * (size_t)K;
    const unsigned short* gw0 = Wt + (size_t)(col0 + w * 32 + (lane >> 2)) * K + (lane & 3) * 8;
    const unsigned short* gw1 = gw0 + 16 * (size_t)K;
    unsigned short* la0 = As + (w * 32) * 32;        // wave-uniform LDS bases
    unsigned short* la1 = As + (w * 32 + 16) * 32;
    unsigned short* lw0 = Ws + (w * 32) * 32;
    unsigned short* lw1 = Ws + (w * 32 + 16) * 32;

    int wm = (w & 1) * 64, wn = (w >> 1) * 64;
    const unsigned short* Afr = As + (size_t)(wm + l15) * 32 + quad * 8;
    const unsigned short* Wfr = Ws + (size_t)(wn + l15) * 32 + quad * 8;

    f32x4 acc[4][4] = {};

    for (int k0 = 0; k0 < K; k0 += 32) {
        gld16(ga0 + k0, la0);
        gld16(ga1 + k0, la1);
        gld16(gw0 + k0, lw0);
        gld16(gw1 + k0, lw1);
        __syncthreads();   // drains vmcnt for the global_load_lds
        bf16x8 af[4], wf[4];
#pragma unroll
        for (int i = 0; i < 4; i++) af[i] = *(const bf16x8*)(Afr + i * 16 * 32);
#pragma unroll
        for (int j = 0; j < 4; j++) wf[j] = *(const bf16x8*)(Wfr + j * 16 * 32);
#pragma unroll
        for (int i = 0; i < 4; i++)
#pragma unroll
            for (int j = 0; j < 4; j++)
                acc[i][j] = __builtin_amdgcn_mfma_f32_16x16x32_bf16(af[i], wf[j], acc[i][j], 0, 0, 0);
        __syncthreads();
    }

    // C/D layout: col = lane&15, row = quad*4 + reg
#pragma unroll
    for (int i = 0; i < 4; i++) {
        int r = row0 + wm + i * 16 + quad * 4;
#pragma unroll
        for (int j = 0; j < 4; j++) {
            int cc = col0 + wn + j * 16 + l15;
            float* cp = C + (size_t)r * N + cc;
#pragma unroll
            for (int reg = 0; reg < 4; reg++)
                cp[(size_t)reg * N] = acc[i][j][reg];
        }
    }
}

// -------------------- expert BN+swish + gate mix -> mix bf16 [t][b][d] --------------------
__global__ __launch_bounds__(512) void k_mix(const float* __restrict__ eh,
                                             const float* __restrict__ scale,
                                             const float* __restrict__ shift,
                                             const float* __restrict__ gates,
                                             unsigned short* __restrict__ mix) {
    int b = blockIdx.x, d = threadIdx.x;
    __shared__ float gl[2][8];
    if (threadIdx.x < 16)
        gl[threadIdx.x >> 3][threadIdx.x & 7] =
            gates[(size_t)(threadIdx.x >> 3) * (B_ * E_) + (size_t)b * E_ + (threadIdx.x & 7)];
    __syncthreads();
    float a0 = 0.f, a1 = 0.f;
#pragma unroll
    for (int e = 0; e < E_; e++) {
        int n = e * D_ + d;
        float v = eh[(size_t)b * (E_ * D_) + n];
        float hv = scale[n] * v + shift[n];
        float sw = swishf(hv);
        a0 += gl[0][e] * sw;
        a1 += gl[1][e] * sw;
    }
    mix[(size_t)b * D_ + d] = f2bf(a0);
    mix[(size_t)(B_ * D_) + (size_t)b * D_ + d] = f2bf(a1);
}

// -------------------- task BN+swish + final heads --------------------
__global__ __launch_bounds__(64) void k_final(const float* __restrict__ th,
                                              const float* __restrict__ scale,
                                              const float* __restrict__ shift,
                                              const float* __restrict__ fwa,
                                              const float* __restrict__ fba,
                                              const float* __restrict__ fwb,
                                              const float* __restrict__ fbb,
                                              float* __restrict__ out) {
    __shared__ float t0[D_], t1[D_];
    int b = blockIdx.x, tid = threadIdx.x;
    for (int i = tid; i < D_; i += 64) {
        float v0 = th[(size_t)b * D_ + i];
        t0[i] = swishf(scale[i] * v0 + shift[i]);
        float v1 = th[(size_t)(B_ * D_) + (size_t)b * D_ + i];
        t1[i] = swishf(scale[D_ + i] * v1 + shift[D_ + i]);
    }
    __syncthreads();
    if (tid < 32) {
        float acc = fba[tid];
        for (int d = 0; d < D_; d++) acc += t0[d] * fwa[d * 32 + tid];
        out[(size_t)b * OUTW + tid] = acc;
    } else if (tid < 34) {
        int j = tid - 32;
        float acc = fbb[j];
        for (int d = 0; d < D_; d++) acc += t1[d] * fwb[d * 2 + j];
        out[(size_t)b * OUTW + tid] = acc;
    }
}

extern "C" void kernel_launch(void* const* d_in, const int* in_sizes, int n_in,
                              void* d_out, int out_size, void* d_ws, size_t ws_size,
                              hipStream_t stream) {
    const float* x        = (const float*)d_in[0];
    const float* w0       = (const float*)d_in[1];
    const float* b0       = (const float*)d_in[2];
    const float* bn0_g    = (const float*)d_in[3];
    const float* bn0_b    = (const float*)d_in[4];
    const float* gate_w   = (const float*)d_in[5];
    const float* gate_b   = (const float*)d_in[6];
    const float* exp_w    = (const float*)d_in[7];
    const float* exp_bn_g = (const float*)d_in[8];
    const float* exp_bn_b = (const float*)d_in[9];
    const float* task_w   = (const float*)d_in[10];
    const float* task_bn_g= (const float*)d_in[11];
    const float* task_bn_b= (const float*)d_in[12];
    const float* fwa      = (const float*)d_in[13];
    const float* fba      = (const float*)d_in[14];
    const float* fwb      = (const float*)d_in[15];
    const float* fbb      = (const float*)d_in[16];
    float* out = (float*)d_out;

    // workspace layout (float units). Aliases: th <- eh (eh dead after k_mix);
    // mixbf <- h0 region (h0 raw dead after k_bnswish_gates).
    float* ws = (float*)d_ws;
    float* eh            = ws;                               // 33,554,432 f (B*E*D)
    float* h0            = ws + 33554432;                    //  8,388,608 f (B*F)
    float* th            = eh;                               //  8,388,608 f (T*B*D)
    unsigned short* mixbf= (unsigned short*)h0;              //  8,388,608 u16 (T*B*D)
    unsigned short* h0bf = (unsigned short*)(ws + 41943040); //  8,388,608 u16
    unsigned short* wtE  = (unsigned short*)(ws + 46137344); //  4,194,304 u16 (E*D x F)
    unsigned short* twt  = (unsigned short*)(ws + 48234496); //    524,288 u16 (T*D x D)
    float* gates = ws + 48496640;                            //    131,072 f
    float* sc0   = ws + 48627712;
    float* sh0   = sc0 + 1024;
    float* scE   = sh0 + 1024;
    float* shE   = scE + 4096;
    float* scT   = shE + 4096;
    float* shT   = scT + 1024;
    float* psum  = shT + 1024;                               //    131,072 f
    float* psq   = psum + 131072;                            //    131,072 f
    // total ~= 195.6 MB

    // 0) weight transpose-converts (bf16, K-contiguous rows)
    k_wt<<<dim3(32, 16, 8), 256, 0, stream>>>(exp_w, wtE, F_, D_);     // [E][F][D] -> [E*D][F]
    k_wt<<<dim3(16, 16, 2), 256, 0, stream>>>(task_w, twt, D_, D_);    // [T][D][D] -> [T][D][D]^T
    // 1) split linear -> h0 raw (fp32)
    k_split<<<dim3(128, 16), 256, 0, stream>>>(x, w0, b0, h0);
    // 2) BN0 stats
    k_stats_a<<<dim3(16, 32, 1), 256, 0, stream>>>(h0, 0ull, F_, psum, psq);
    k_stats_b<<<dim3(16, 1, 1), 64, 0, stream>>>(psum, psq, F_, 32, bn0_g, bn0_b, 0ull, sc0, sh0, 0ull);
    // 3) BN0 apply + swish -> h0bf (bf16) + gate softmax
    k_bnswish_gates<<<dim3(B_), 256, 0, stream>>>(h0, sc0, sh0, gate_w, gate_b, h0bf, gates);
    // 4) expert GEMM (bf16 MFMA): eh[b, e*512+d] f32
    k_gemm_bf16<<<dim3(64, 32, 1), 256, 0, stream>>>(h0bf, 0ull, wtE, 0ull, eh, 0ull, F_);
    // 5) expert BN stats
    k_stats_a<<<dim3(64, 32, 1), 256, 0, stream>>>(eh, 0ull, E_ * D_, psum, psq);
    k_stats_b<<<dim3(64, 1, 1), 64, 0, stream>>>(psum, psq, E_ * D_, 32, exp_bn_g, exp_bn_b, 0ull, scE, shE, 0ull);
    // 6) expert BN apply + swish + gate mix -> mixbf (bf16)
    k_mix<<<dim3(B_), 512, 0, stream>>>(eh, scE, shE, gates, mixbf);
    // 7) task GEMM (bf16 MFMA): th[t,b,k] f32 (aliases eh)
    k_gemm_bf16<<<dim3(64, 4, 2), 256, 0, stream>>>(mixbf, (unsigned long long)(B_ * D_),
                                                    twt, (unsigned long long)(D_ * D_),
                                                    th, (unsigned long long)(B_ * D_), D_);
    // 8) task BN stats
    k_stats_a<<<dim3(8, 32, 2), 256, 0, stream>>>(th, (unsigned long long)(B_ * D_), D_, psum, psq);
    k_stats_b<<<dim3(8, 1, 2), 64, 0, stream>>>(psum, psq, D_, 32, task_bn_g, task_bn_b, 512ull, scT, shT, 512ull);
    // 9) task BN apply + swish + final heads -> out [B, 34]
    k_final<<<dim3(B_), 64, 0, stream>>>(th, scT, shT, fwa, fba, fwb, fbb, out);
}

// Round 3
// 750.096 us; speedup vs baseline: 2.3364x; 1.1097x over previous
//
#include <hip/hip_runtime.h>
#include <math.h>

#define B_ 8192
#define IN_ 8000
#define C_ 16
#define S_ 500
#define O_ 64
#define F_ 1024
#define E_ 8
#define D_ 512
#define T_ 2
#define OUTW 34
#define EPS_ 1e-5f

typedef __attribute__((ext_vector_type(8))) short bf16x8;
typedef __attribute__((ext_vector_type(4))) float f32x4;

__device__ __forceinline__ float swishf(float x) {
    return x / (1.0f + __expf(-x));
}

// round-to-nearest-even f32 -> bf16 bits
__device__ __forceinline__ unsigned short f2bf(float f) {
    union { float f; unsigned u; } c;
    c.f = f;
    unsigned r = c.u + 0x7fffu + ((c.u >> 16) & 1u);
    return (unsigned short)(r >> 16);
}
__device__ __forceinline__ float bf2f(unsigned short b) {
    union { unsigned u; float f; } c;
    c.u = ((unsigned)b) << 16;
    return c.f;
}

// async global->LDS, 16B per lane; LDS dest is wave-uniform base + lane*16
__device__ __forceinline__ void gld16(const void* g, void* l) {
    __builtin_amdgcn_global_load_lds(
        (const __attribute__((address_space(1))) void*)g,
        (__attribute__((address_space(3))) void*)l, 16, 0, 0);
}

// -------------------- SplitLinear + fused BN0 column partial stats --------------------
// h0[b, c*64+o] = sum_s x[b,c*500+s]*w0[c,o,s] + b0
// grid (B/128, C), block 256; per-thread 8 rows x 4 cols; KT=20 (25 tiles of 20 = 500)
// psum/psq: [64 rowblocks][F_] column partials (sum over the block's 128 rows)
__global__ __launch_bounds__(256) void k_split(const float* __restrict__ x,
                                               const float* __restrict__ w0,
                                               const float* __restrict__ b0,
                                               float* __restrict__ h0,
                                               float* __restrict__ psum,
                                               float* __restrict__ psq) {
    const int KT = 20;
    __shared__ __align__(16) float xs[KT][132];
    __shared__ __align__(16) float wsh[KT][68];
    int tid = threadIdx.x;
    int tx = tid & 15, ty = tid >> 4;          // cols tx*4..+3, rows ty*8..+7
    int c = blockIdx.y;
    int brow0 = blockIdx.x * 128;
    const float* xp = x + (size_t)brow0 * IN_ + c * S_;
    const float* wp = w0 + (size_t)c * O_ * S_;
    float acc[8][4];
#pragma unroll
    for (int r = 0; r < 8; r++)
#pragma unroll
        for (int j = 0; j < 4; j++) acc[r][j] = 0.f;

    for (int k0 = 0; k0 < S_; k0 += KT) {
#pragma unroll
        for (int i = 0; i < 10; i++) {          // 128*20 = 2560 x-elements
            int li = tid + i * 256;
            int bi = li / KT, k = li % KT;
            xs[k][bi] = xp[(size_t)bi * IN_ + k0 + k];
        }
#pragma unroll
        for (int i = 0; i < 5; i++) {           // 64*20 = 1280 w-elements
            int li = tid + i * 256;
            int oi = li / KT, k = li % KT;
            wsh[k][oi] = wp[oi * S_ + k0 + k];
        }
        __syncthreads();
#pragma unroll
        for (int k = 0; k < KT; k++) {
            float a[8], wv[4];
#pragma unroll
            for (int r = 0; r < 8; r++) a[r] = xs[k][ty * 8 + r];
#pragma unroll
            for (int j = 0; j < 4; j++) wv[j] = wsh[k][tx * 4 + j];
#pragma unroll
            for (int r = 0; r < 8; r++)
#pragma unroll
                for (int j = 0; j < 4; j++) acc[r][j] += a[r] * wv[j];
        }
        __syncthreads();
    }

    // bias + store (float4 per row) + per-thread column partials
    float s[4] = {0.f, 0.f, 0.f, 0.f}, q[4] = {0.f, 0.f, 0.f, 0.f};
    int ocol0 = c * O_ + tx * 4;
    float bb[4];
#pragma unroll
    for (int j = 0; j < 4; j++) bb[j] = b0[ocol0 + j];
#pragma unroll
    for (int r = 0; r < 8; r++) {
        float4 v;
        float vv[4];
#pragma unroll
        for (int j = 0; j < 4; j++) {
            vv[j] = acc[r][j] + bb[j];
            s[j] += vv[j];
            q[j] += vv[j] * vv[j];
        }
        v.x = vv[0]; v.y = vv[1]; v.z = vv[2]; v.w = vv[3];
        *(float4*)(h0 + (size_t)(brow0 + ty * 8 + r) * F_ + ocol0) = v;
    }
    // reduce over ty: within wave, lanes +16,+32 are ty+1..ty+3 (same tx)
#pragma unroll
    for (int j = 0; j < 4; j++) {
        s[j] += __shfl_down(s[j], 32, 64); s[j] += __shfl_down(s[j], 16, 64);
        q[j] += __shfl_down(q[j], 32, 64); q[j] += __shfl_down(q[j], 16, 64);
    }
    float* red = &xs[0][0];   // reuse LDS: [0..255]=sum, [256..511]=sq
    int wv_ = tid >> 6, lane = tid & 63;
    if (lane < 16) {
#pragma unroll
        for (int j = 0; j < 4; j++) {
            red[(wv_ * 16 + lane) * 4 + j] = s[j];
            red[256 + (wv_ * 16 + lane) * 4 + j] = q[j];
        }
    }
    __syncthreads();
    if (tid < 64) {
        int txc = tid >> 2, j = tid & 3;
        float ss = 0.f, qq = 0.f;
#pragma unroll
        for (int w = 0; w < 4; w++) {
            ss += red[(w * 16 + txc) * 4 + j];
            qq += red[256 + (w * 16 + txc) * 4 + j];
        }
        size_t idx = (size_t)blockIdx.x * F_ + c * O_ + tid;
        psum[idx] = ss; psq[idx] = qq;
    }
}

// -------------------- Column stats finalize: scale = g*rsqrt(var+eps); shift = beta - mean*scale --------------------
// grid (N/64, 1, Z), block 64; partials layout [(z*YS + y)*N + n]
__global__ __launch_bounds__(64) void k_stats_b(const float* __restrict__ psum,
                                                const float* __restrict__ psq,
                                                int N, int YS,
                                                const float* __restrict__ g,
                                                const float* __restrict__ beta,
                                                unsigned long long gslab,
                                                float* __restrict__ scale,
                                                float* __restrict__ shift,
                                                unsigned long long oslab) {
    int n = blockIdx.x * 64 + threadIdx.x;
    int z = blockIdx.z;
    float s = 0.f, q = 0.f;
    for (int y = 0; y < YS; y++) {
        size_t idx = ((size_t)(z * YS + y)) * N + n;
        s += psum[idx]; q += psq[idx];
    }
    float mean = s * (1.0f / B_);
    float var = q * (1.0f / B_) - mean * mean;
    float sc = g[z * gslab + n] * rsqrtf(var + EPS_);
    scale[z * oslab + n] = sc;
    shift[z * oslab + n] = beta[z * gslab + n] - mean * sc;
}

// -------------------- transpose-convert: in [Z][K][N] f32 -> out [Z][N][K] bf16 --------------------
__global__ __launch_bounds__(256) void k_wt(const float* __restrict__ in,
                                            unsigned short* __restrict__ out,
                                            int K, int N) {
    __shared__ float t[32][33];
    int k0 = blockIdx.x * 32, n0 = blockIdx.y * 32, z = blockIdx.z;
    const float* ip = in + (size_t)z * K * N;
    unsigned short* op = out + (size_t)z * N * K;
    int tn = threadIdx.x & 31, tk = threadIdx.x >> 5;
#pragma unroll
    for (int p = 0; p < 4; p++) {
        int k = tk + p * 8;
        t[k][tn] = ip[(size_t)(k0 + k) * N + n0 + tn];
    }
    __syncthreads();
    int tk2 = threadIdx.x & 31, tn2 = threadIdx.x >> 5;
#pragma unroll
    for (int p = 0; p < 4; p++) {
        int n = tn2 + p * 8;
        op[(size_t)(n0 + n) * K + k0 + tk2] = f2bf(t[tk2][n]);
    }
}

// -------------------- BN+swish -> h0bf (bf16) + per-task gate softmax --------------------
__global__ __launch_bounds__(256) void k_bnswish_gates(const float* __restrict__ h0,
                                                       const float* __restrict__ scale,
                                                       const float* __restrict__ shift,
                                                       const float* __restrict__ gate_w,
                                                       const float* __restrict__ gate_b,
                                                       unsigned short* __restrict__ h0bf,
                                                       float* __restrict__ gates) {
    int b = blockIdx.x, tid = threadIdx.x;
    float part[16];
#pragma unroll
    for (int i = 0; i < 16; i++) part[i] = 0.f;
    const float* row = h0 + (size_t)b * F_;
    unsigned short* ob = h0bf + (size_t)b * F_;
#pragma unroll
    for (int it = 0; it < 4; it++) {
        int f = tid + it * 256;
        float v = row[f];
        float hv = scale[f] * v + shift[f];
        float sw = swishf(hv);
        ob[f] = f2bf(sw);
        const float* gw0 = gate_w + (size_t)f * E_;
        const float* gw1 = gate_w + (size_t)(F_ * E_) + (size_t)f * E_;
#pragma unroll
        for (int e = 0; e < E_; e++) part[e] += sw * gw0[e];
#pragma unroll
        for (int e = 0; e < E_; e++) part[8 + e] += sw * gw1[e];
    }
#pragma unroll
    for (int i = 0; i < 16; i++) {
        float v = part[i];
        for (int off = 32; off > 0; off >>= 1) v += __shfl_down(v, off, 64);
        part[i] = v;
    }
    __shared__ float red[4][16];
    __shared__ float gfin[16];
    int wave = tid >> 6, lane = tid & 63;
    if (lane == 0) {
#pragma unroll
        for (int i = 0; i < 16; i++) red[wave][i] = part[i];
    }
    __syncthreads();
    if (tid < 16) {
        float v = red[0][tid] + red[1][tid] + red[2][tid] + red[3][tid];
        int t = tid >> 3, e = tid & 7;
        gfin[tid] = v + gate_b[t * E_ + e];
    }
    __syncthreads();
    if (tid < 2) {
        float mx = -1e30f;
#pragma unroll
        for (int e = 0; e < 8; e++) mx = fmaxf(mx, gfin[tid * 8 + e]);
        float ex[8], sum = 0.f;
#pragma unroll
        for (int e = 0; e < 8; e++) { ex[e] = __expf(gfin[tid * 8 + e] - mx); sum += ex[e]; }
        float inv = 1.0f / sum;
#pragma unroll
        for (int e = 0; e < 8; e++)
            gates[(size_t)tid * (B_ * E_) + (size_t)b * E_ + e] = ex[e] * inv;
    }
}

// -------------------- bf16 MFMA GEMM + fused column partial stats, bf16 C --------------------
// A: [M][K] bf16 k-contig; Wt: [N][K] bf16 k-contig; C: [M][N] bf16.
// psum/psq: [(z*gridDim.x + bx)][N] column partials over the block's 128 rows (exact f32).
// grid (M/128, N/128, Z), block 256 (4 waves, 2x2 of 64x64 wave tiles)
__global__ __launch_bounds__(256) void k_gemm_bf16(const unsigned short* __restrict__ A,
                                                   unsigned long long aslab,
                                                   const unsigned short* __restrict__ Wt,
                                                   unsigned long long wslab,
                                                   unsigned short* __restrict__ C,
                                                   unsigned long long cslab, int K,
                                                   float* __restrict__ psum,
                                                   float* __restrict__ psq) {
    __shared__ __align__(16) unsigned short As[128 * 32];
    __shared__ __align__(16) unsigned short Ws[128 * 32];
    int z = blockIdx.z;
    A  += (size_t)z * aslab;
    Wt += (size_t)z * wslab;
    C  += (size_t)z * cslab;
    const int N = gridDim.y * 128;
    int row0 = blockIdx.x * 128, col0 = blockIdx.y * 128;
    int tid = threadIdx.x;
    int w = tid >> 6, lane = tid & 63;
    int l15 = lane & 15, quad = lane >> 4;

    const unsigned short* ga0 = A  + (size_t)(row0 + w * 32 + (lane >> 2)) * K + (lane & 3) * 8;
    const unsigned short* ga1 = ga0 + 16 * (size_t)K;
    const unsigned short* gw0 = Wt + (size_t)(col0 + w * 32 + (lane >> 2)) * K + (lane & 3) * 8;
    const unsigned short* gw1 = gw0 + 16 * (size_t)K;
    unsigned short* la0 = As + (w * 32) * 32;
    unsigned short* la1 = As + (w * 32 + 16) * 32;
    unsigned short* lw0 = Ws + (w * 32) * 32;
    unsigned short* lw1 = Ws + (w * 32 + 16) * 32;

    int wm = (w & 1) * 64, wn = (w >> 1) * 64;
    const unsigned short* Afr = As + (size_t)(wm + l15) * 32 + quad * 8;
    const unsigned short* Wfr = Ws + (size_t)(wn + l15) * 32 + quad * 8;

    f32x4 acc[4][4] = {};

    for (int k0 = 0; k0 < K; k0 += 32) {
        gld16(ga0 + k0, la0);
        gld16(ga1 + k0, la1);
        gld16(gw0 + k0, lw0);
        gld16(gw1 + k0, lw1);
        __syncthreads();
        bf16x8 af[4], wf[4];
#pragma unroll
        for (int i = 0; i < 4; i++) af[i] = *(const bf16x8*)(Afr + i * 16 * 32);
#pragma unroll
        for (int j = 0; j < 4; j++) wf[j] = *(const bf16x8*)(Wfr + j * 16 * 32);
#pragma unroll
        for (int i = 0; i < 4; i++)
#pragma unroll
            for (int j = 0; j < 4; j++)
                acc[i][j] = __builtin_amdgcn_mfma_f32_16x16x32_bf16(af[i], wf[j], acc[i][j], 0, 0, 0);
        __syncthreads();
    }

    // C store (bf16). C/D layout: col = lane&15, row = quad*4 + reg
#pragma unroll
    for (int i = 0; i < 4; i++) {
        int r = row0 + wm + i * 16 + quad * 4;
#pragma unroll
        for (int j = 0; j < 4; j++) {
            int cc = col0 + wn + j * 16 + l15;
            unsigned short* cp = C + (size_t)r * N + cc;
#pragma unroll
            for (int reg = 0; reg < 4; reg++)
                cp[(size_t)reg * N] = f2bf(acc[i][j][reg]);
        }
    }

    // fused column partial stats: per lane, col j covers 16 rows (fixed quad);
    // shuffle over quad completes the wave's 64 rows; two waves share each col.
    float* red = (float*)As;   // [0..255]=sum pairs, [256..511]=sq pairs
    float sj[4], qj[4];
#pragma unroll
    for (int j = 0; j < 4; j++) {
        float s = 0.f, q = 0.f;
#pragma unroll
        for (int i = 0; i < 4; i++)
#pragma unroll
            for (int reg = 0; reg < 4; reg++) {
                float v = acc[i][j][reg];
                s += v; q += v * v;
            }
        s += __shfl_down(s, 32, 64); s += __shfl_down(s, 16, 64);
        q += __shfl_down(q, 32, 64); q += __shfl_down(q, 16, 64);
        sj[j] = s; qj[j] = q;
    }
    if (lane < 16) {
#pragma unroll
        for (int j = 0; j < 4; j++) {
            int cib = wn + j * 16 + lane;          // col in block, 0..127
            red[cib * 2 + (w & 1)] = sj[j];
            red[256 + cib * 2 + (w & 1)] = qj[j];
        }
    }
    __syncthreads();
    if (tid < 128) {
        float s = red[tid * 2] + red[tid * 2 + 1];
        float q = red[256 + tid * 2] + red[256 + tid * 2 + 1];
        size_t row = (size_t)z * gridDim.x + blockIdx.x;
        psum[row * N + col0 + tid] = s;
        psq[row * N + col0 + tid] = q;
    }
}

// -------------------- expert BN+swish + gate mix -> mix bf16 [t][b][d] --------------------
__global__ __launch_bounds__(512) void k_mix(const unsigned short* __restrict__ eh,
                                             const float* __restrict__ scale,
                                             const float* __restrict__ shift,
                                             const float* __restrict__ gates,
                                             unsigned short* __restrict__ mix) {
    int b = blockIdx.x, d = threadIdx.x;
    __shared__ float gl[2][8];
    if (threadIdx.x < 16)
        gl[threadIdx.x >> 3][threadIdx.x & 7] =
            gates[(size_t)(threadIdx.x >> 3) * (B_ * E_) + (size_t)b * E_ + (threadIdx.x & 7)];
    __syncthreads();
    float a0 = 0.f, a1 = 0.f;
#pragma unroll
    for (int e = 0; e < E_; e++) {
        int n = e * D_ + d;
        float v = bf2f(eh[(size_t)b * (E_ * D_) + n]);
        float hv = scale[n] * v + shift[n];
        float sw = swishf(hv);
        a0 += gl[0][e] * sw;
        a1 += gl[1][e] * sw;
    }
    mix[(size_t)b * D_ + d] = f2bf(a0);
    mix[(size_t)(B_ * D_) + (size_t)b * D_ + d] = f2bf(a1);
}

// -------------------- task BN+swish + final heads --------------------
__global__ __launch_bounds__(64) void k_final(const unsigned short* __restrict__ th,
                                              const float* __restrict__ scale,
                                              const float* __restrict__ shift,
                                              const float* __restrict__ fwa,
                                              const float* __restrict__ fba,
                                              const float* __restrict__ fwb,
                                              const float* __restrict__ fbb,
                                              float* __restrict__ out) {
    __shared__ float t0[D_], t1[D_];
    int b = blockIdx.x, tid = threadIdx.x;
    for (int i = tid; i < D_; i += 64) {
        float v0 = bf2f(th[(size_t)b * D_ + i]);
        t0[i] = swishf(scale[i] * v0 + shift[i]);
        float v1 = bf2f(th[(size_t)(B_ * D_) + (size_t)b * D_ + i]);
        t1[i] = swishf(scale[D_ + i] * v1 + shift[D_ + i]);
    }
    __syncthreads();
    if (tid < 32) {
        float acc = fba[tid];
        for (int d = 0; d < D_; d++) acc += t0[d] * fwa[d * 32 + tid];
        out[(size_t)b * OUTW + tid] = acc;
    } else if (tid < 34) {
        int j = tid - 32;
        float acc = fbb[j];
        for (int d = 0; d < D_; d++) acc += t1[d] * fwb[d * 2 + j];
        out[(size_t)b * OUTW + tid] = acc;
    }
}

extern "C" void kernel_launch(void* const* d_in, const int* in_sizes, int n_in,
                              void* d_out, int out_size, void* d_ws, size_t ws_size,
                              hipStream_t stream) {
    const float* x        = (const float*)d_in[0];
    const float* w0       = (const float*)d_in[1];
    const float* b0       = (const float*)d_in[2];
    const float* bn0_g    = (const float*)d_in[3];
    const float* bn0_b    = (const float*)d_in[4];
    const float* gate_w   = (const float*)d_in[5];
    const float* gate_b   = (const float*)d_in[6];
    const float* exp_w    = (const float*)d_in[7];
    const float* exp_bn_g = (const float*)d_in[8];
    const float* exp_bn_b = (const float*)d_in[9];
    const float* task_w   = (const float*)d_in[10];
    const float* task_bn_g= (const float*)d_in[11];
    const float* task_bn_b= (const float*)d_in[12];
    const float* fwa      = (const float*)d_in[13];
    const float* fba      = (const float*)d_in[14];
    const float* fwb      = (const float*)d_in[15];
    const float* fbb      = (const float*)d_in[16];
    float* out = (float*)d_out;

    // workspace layout (float units). Aliases (disjoint lifetimes):
    //   th (u16) <- eh region (eh dead after k_mix)
    //   mixbf (u16) <- h0 region (h0 raw dead after k_bnswish_gates)
    float* ws = (float*)d_ws;
    unsigned short* ehbf = (unsigned short*)ws;              // B*E*D u16 -> 16,777,216 f
    float* h0            = ws + 16777216;                    //  8,388,608 f (B*F)
    unsigned short* thbf = ehbf;                             // T*B*D u16 (alias)
    unsigned short* mixbf= (unsigned short*)h0;              // T*B*D u16 (alias)
    unsigned short* h0bf = (unsigned short*)(ws + 25165824); // B*F u16 -> 4,194,304 f
    unsigned short* wtE  = (unsigned short*)(ws + 29360128); // E*D*F u16 -> 2,097,152 f
    unsigned short* twt  = (unsigned short*)(ws + 31457280); // T*D*D u16 -> 262,144 f
    float* gates = ws + 31719424;                            //    131,072 f
    float* sc0   = ws + 31850496;                            // 1024
    float* sh0   = sc0 + 1024;
    float* scE   = sh0 + 1024;                               // 4096
    float* shE   = scE + 4096;
    float* scT   = shE + 4096;                               // 1024
    float* shT   = scT + 1024;
    float* psum  = shT + 1024;                               // 262,144 (max: 64 x 4096)
    float* psq   = psum + 262144;                            // 262,144
    // total ~= 130 MB

    // 0) weight transpose-converts (bf16, K-contiguous rows)
    k_wt<<<dim3(32, 16, 8), 256, 0, stream>>>(exp_w, wtE, F_, D_);   // [E][F][D] -> [E*D][F]
    k_wt<<<dim3(16, 16, 2), 256, 0, stream>>>(task_w, twt, D_, D_);  // [T][D][D] -> [T][D][D]^T
    // 1) split linear -> h0 (f32) + fused BN0 partial stats
    k_split<<<dim3(64, 16), 256, 0, stream>>>(x, w0, b0, h0, psum, psq);
    k_stats_b<<<dim3(16, 1, 1), 64, 0, stream>>>(psum, psq, F_, 64, bn0_g, bn0_b, 0ull, sc0, sh0, 0ull);
    // 2) BN0 apply + swish -> h0bf (bf16) + gate softmax
    k_bnswish_gates<<<dim3(B_), 256, 0, stream>>>(h0, sc0, sh0, gate_w, gate_b, h0bf, gates);
    // 3) expert GEMM (bf16 MFMA) -> ehbf + fused expert-BN partial stats
    k_gemm_bf16<<<dim3(64, 32, 1), 256, 0, stream>>>(h0bf, 0ull, wtE, 0ull, ehbf, 0ull, F_, psum, psq);
    k_stats_b<<<dim3(64, 1, 1), 64, 0, stream>>>(psum, psq, E_ * D_, 64, exp_bn_g, exp_bn_b, 0ull, scE, shE, 0ull);
    // 4) expert BN apply + swish + gate mix -> mixbf (bf16)
    k_mix<<<dim3(B_), 512, 0, stream>>>(ehbf, scE, shE, gates, mixbf);
    // 5) task GEMM (bf16 MFMA) -> thbf + fused task-BN partial stats
    k_gemm_bf16<<<dim3(64, 4, 2), 256, 0, stream>>>(mixbf, (unsigned long long)(B_ * D_),
                                                    twt, (unsigned long long)(D_ * D_),
                                                    thbf, (unsigned long long)(B_ * D_), D_,
                                                    psum, psq);
    k_stats_b<<<dim3(8, 1, 2), 64, 0, stream>>>(psum, psq, D_, 64, task_bn_g, task_bn_b, 512ull, scT, shT, 512ull);
    // 6) task BN apply + swish + final heads -> out [B, 34]
    k_final<<<dim3(B_), 64, 0, stream>>>(thbf, scT, shT, fwa, fba, fwb, fbb, out);
}

// Round 4
// 689.558 us; speedup vs baseline: 2.5415x; 1.0878x over previous
//
#include <hip/hip_runtime.h>
#include <math.h>

#define B_ 8192
#define IN_ 8000
#define C_ 16
#define S_ 500
#define O_ 64
#define F_ 1024
#define E_ 8
#define D_ 512
#define T_ 2
#define OUTW 34
#define EPS_ 1e-5f

typedef __attribute__((ext_vector_type(8))) short bf16x8;
typedef __attribute__((ext_vector_type(4))) float f32x4;

__device__ __forceinline__ float swishf(float x) {
    return x / (1.0f + __expf(-x));
}

// round-to-nearest-even f32 -> bf16 bits
__device__ __forceinline__ unsigned short f2bf(float f) {
    union { float f; unsigned u; } c;
    c.f = f;
    unsigned r = c.u + 0x7fffu + ((c.u >> 16) & 1u);
    return (unsigned short)(r >> 16);
}
__device__ __forceinline__ float bf2f(unsigned short b) {
    union { unsigned u; float f; } c;
    c.u = ((unsigned)b) << 16;
    return c.f;
}

// async global->LDS, 16B per lane; LDS dest is wave-uniform base + lane*16
__device__ __forceinline__ void gld16(const void* g, void* l) {
    __builtin_amdgcn_global_load_lds(
        (const __attribute__((address_space(1))) void*)g,
        (__attribute__((address_space(3))) void*)l, 16, 0, 0);
}

// -------------------- SplitLinear via bf16 MFMA + fused bias + BN0 partial stats --------------------
// h0raw[b, c*64+col] = bf16( sum_s x[b,c*500+s]*w0[c,col,s] + b0 )  (f32 accumulate, bf16 store)
// grid (B/128, C), block 256 (4 waves; wave w owns rows w*32..w*32+31, all 64 cols)
// K = 500 zero-padded to 8 tiles of 64. psum/psq[bx][F]: column partials over block's 128 rows.
__global__ __launch_bounds__(256) void k_split(const float* __restrict__ x,
                                               const float* __restrict__ w0,
                                               const float* __restrict__ b0,
                                               unsigned short* __restrict__ h0raw,
                                               float* __restrict__ psum,
                                               float* __restrict__ psq) {
    __shared__ __align__(16) unsigned short As[128 * 72];  // [row][72] padded
    __shared__ __align__(16) unsigned short Bs[64 * 72];
    int tid = threadIdx.x;
    int c = blockIdx.y;
    int brow0 = blockIdx.x * 128;
    const float* xp = x + (size_t)brow0 * IN_ + c * S_;
    const float* wp = w0 + (size_t)c * O_ * S_;

    int w = tid >> 6, lane = tid & 63;
    int l15 = lane & 15, quad = lane >> 4;
    int wm = w * 32;

    f32x4 acc[2][4] = {};

    for (int k0 = 0; k0 < 512; k0 += 64) {
        // stage A: 128 rows x 64 k (f32 -> bf16), 2048 float4 loads
#pragma unroll
        for (int i = 0; i < 8; i++) {
            int li = tid + i * 256;
            int row = li >> 4, c4 = li & 15;
            int gk = k0 + c4 * 4;
            float4 v = make_float4(0.f, 0.f, 0.f, 0.f);
            if (gk + 3 < S_) v = *(const float4*)(xp + (size_t)row * IN_ + gk);
            unsigned short u[4] = { f2bf(v.x), f2bf(v.y), f2bf(v.z), f2bf(v.w) };
            *(ushort4*)&As[row * 72 + c4 * 4] = *(ushort4*)u;
        }
        // stage W: 64 rows x 64 k
#pragma unroll
        for (int i = 0; i < 4; i++) {
            int li = tid + i * 256;
            int row = li >> 4, c4 = li & 15;
            int gk = k0 + c4 * 4;
            float4 v = make_float4(0.f, 0.f, 0.f, 0.f);
            if (gk + 3 < S_) v = *(const float4*)(wp + (size_t)row * S_ + gk);
            unsigned short u[4] = { f2bf(v.x), f2bf(v.y), f2bf(v.z), f2bf(v.w) };
            *(ushort4*)&Bs[row * 72 + c4 * 4] = *(ushort4*)u;
        }
        __syncthreads();
#pragma unroll
        for (int kk = 0; kk < 64; kk += 32) {
            bf16x8 af[2], wf[4];
#pragma unroll
            for (int i = 0; i < 2; i++)
                af[i] = *(const bf16x8*)&As[(wm + i * 16 + l15) * 72 + kk + quad * 8];
#pragma unroll
            for (int j = 0; j < 4; j++)
                wf[j] = *(const bf16x8*)&Bs[(j * 16 + l15) * 72 + kk + quad * 8];
#pragma unroll
            for (int i = 0; i < 2; i++)
#pragma unroll
                for (int j = 0; j < 4; j++)
                    acc[i][j] = __builtin_amdgcn_mfma_f32_16x16x32_bf16(af[i], wf[j], acc[i][j], 0, 0, 0);
        }
        __syncthreads();
    }

    // epilogue: bias, bf16 store, column partial stats
    // C/D layout: col = j*16 + l15, row = wm + i*16 + quad*4 + reg
    int colbase = c * O_;
    float sj[4], qj[4];
#pragma unroll
    for (int j = 0; j < 4; j++) {
        int col = j * 16 + l15;
        float bb = b0[colbase + col];
        float s = 0.f, q = 0.f;
#pragma unroll
        for (int i = 0; i < 2; i++) {
#pragma unroll
            for (int reg = 0; reg < 4; reg++) {
                float v = acc[i][j][reg] + bb;
                int rl = wm + i * 16 + quad * 4 + reg;
                h0raw[(size_t)(brow0 + rl) * F_ + colbase + col] = f2bf(v);
                s += v; q += v * v;
            }
        }
        s += __shfl_down(s, 32, 64); s += __shfl_down(s, 16, 64);
        q += __shfl_down(q, 32, 64); q += __shfl_down(q, 16, 64);
        sj[j] = s; qj[j] = q;
    }
    __syncthreads();
    float* red = (float*)As;   // [col*4 + wave], then +256 for sq
    if (lane < 16) {
#pragma unroll
        for (int j = 0; j < 4; j++) {
            int col = j * 16 + l15;
            red[col * 4 + w] = sj[j];
            red[256 + col * 4 + w] = qj[j];
        }
    }
    __syncthreads();
    if (tid < 64) {
        float ss = red[tid * 4] + red[tid * 4 + 1] + red[tid * 4 + 2] + red[tid * 4 + 3];
        float qq = red[256 + tid * 4] + red[256 + tid * 4 + 1] + red[256 + tid * 4 + 2] + red[256 + tid * 4 + 3];
        size_t idx = (size_t)blockIdx.x * F_ + colbase + tid;
        psum[idx] = ss; psq[idx] = qq;
    }
}

// -------------------- Column stats finalize --------------------
__global__ __launch_bounds__(64) void k_stats_b(const float* __restrict__ psum,
                                                const float* __restrict__ psq,
                                                int N, int YS,
                                                const float* __restrict__ g,
                                                const float* __restrict__ beta,
                                                unsigned long long gslab,
                                                float* __restrict__ scale,
                                                float* __restrict__ shift,
                                                unsigned long long oslab) {
    int n = blockIdx.x * 64 + threadIdx.x;
    int z = blockIdx.z;
    float s = 0.f, q = 0.f;
    for (int y = 0; y < YS; y++) {
        size_t idx = ((size_t)(z * YS + y)) * N + n;
        s += psum[idx]; q += psq[idx];
    }
    float mean = s * (1.0f / B_);
    float var = q * (1.0f / B_) - mean * mean;
    float sc = g[z * gslab + n] * rsqrtf(var + EPS_);
    scale[z * oslab + n] = sc;
    shift[z * oslab + n] = beta[z * gslab + n] - mean * sc;
}

// -------------------- transpose-convert: in [Z][K][N] f32 -> out [Z][N][K] bf16 --------------------
__global__ __launch_bounds__(256) void k_wt(const float* __restrict__ in,
                                            unsigned short* __restrict__ out,
                                            int K, int N) {
    __shared__ float t[32][33];
    int k0 = blockIdx.x * 32, n0 = blockIdx.y * 32, z = blockIdx.z;
    const float* ip = in + (size_t)z * K * N;
    unsigned short* op = out + (size_t)z * N * K;
    int tn = threadIdx.x & 31, tk = threadIdx.x >> 5;
#pragma unroll
    for (int p = 0; p < 4; p++) {
        int k = tk + p * 8;
        t[k][tn] = ip[(size_t)(k0 + k) * N + n0 + tn];
    }
    __syncthreads();
    int tk2 = threadIdx.x & 31, tn2 = threadIdx.x >> 5;
#pragma unroll
    for (int p = 0; p < 4; p++) {
        int n = tn2 + p * 8;
        op[(size_t)(n0 + n) * K + k0 + tk2] = f2bf(t[tk2][n]);
    }
}

// -------------------- BN+swish -> h0bf (bf16) + per-task gate softmax --------------------
__global__ __launch_bounds__(256) void k_bnswish_gates(const unsigned short* __restrict__ h0,
                                                       const float* __restrict__ scale,
                                                       const float* __restrict__ shift,
                                                       const float* __restrict__ gate_w,
                                                       const float* __restrict__ gate_b,
                                                       unsigned short* __restrict__ h0bf,
                                                       float* __restrict__ gates) {
    int b = blockIdx.x, tid = threadIdx.x;
    float part[16];
#pragma unroll
    for (int i = 0; i < 16; i++) part[i] = 0.f;
    const unsigned short* row = h0 + (size_t)b * F_;
    unsigned short* ob = h0bf + (size_t)b * F_;
#pragma unroll
    for (int it = 0; it < 4; it++) {
        int f = tid + it * 256;
        float v = bf2f(row[f]);
        float hv = scale[f] * v + shift[f];
        float sw = swishf(hv);
        ob[f] = f2bf(sw);
        const float* gw0 = gate_w + (size_t)f * E_;
        const float* gw1 = gate_w + (size_t)(F_ * E_) + (size_t)f * E_;
#pragma unroll
        for (int e = 0; e < E_; e++) part[e] += sw * gw0[e];
#pragma unroll
        for (int e = 0; e < E_; e++) part[8 + e] += sw * gw1[e];
    }
#pragma unroll
    for (int i = 0; i < 16; i++) {
        float v = part[i];
        for (int off = 32; off > 0; off >>= 1) v += __shfl_down(v, off, 64);
        part[i] = v;
    }
    __shared__ float red[4][16];
    __shared__ float gfin[16];
    int wave = tid >> 6, lane = tid & 63;
    if (lane == 0) {
#pragma unroll
        for (int i = 0; i < 16; i++) red[wave][i] = part[i];
    }
    __syncthreads();
    if (tid < 16) {
        float v = red[0][tid] + red[1][tid] + red[2][tid] + red[3][tid];
        int t = tid >> 3, e = tid & 7;
        gfin[tid] = v + gate_b[t * E_ + e];
    }
    __syncthreads();
    if (tid < 2) {
        float mx = -1e30f;
#pragma unroll
        for (int e = 0; e < 8; e++) mx = fmaxf(mx, gfin[tid * 8 + e]);
        float ex[8], sum = 0.f;
#pragma unroll
        for (int e = 0; e < 8; e++) { ex[e] = __expf(gfin[tid * 8 + e] - mx); sum += ex[e]; }
        float inv = 1.0f / sum;
#pragma unroll
        for (int e = 0; e < 8; e++)
            gates[(size_t)tid * (B_ * E_) + (size_t)b * E_ + e] = ex[e] * inv;
    }
}

// -------------------- bf16 MFMA GEMM + fused column partial stats, bf16 C --------------------
// grid (M/128, N/128, Z), block 256 (4 waves, 2x2 of 64x64 wave tiles)
__global__ __launch_bounds__(256) void k_gemm_bf16(const unsigned short* __restrict__ A,
                                                   unsigned long long aslab,
                                                   const unsigned short* __restrict__ Wt,
                                                   unsigned long long wslab,
                                                   unsigned short* __restrict__ C,
                                                   unsigned long long cslab, int K,
                                                   float* __restrict__ psum,
                                                   float* __restrict__ psq) {
    __shared__ __align__(16) unsigned short As[128 * 32];
    __shared__ __align__(16) unsigned short Ws[128 * 32];
    int z = blockIdx.z;
    A  += (size_t)z * aslab;
    Wt += (size_t)z * wslab;
    C  += (size_t)z * cslab;
    const int N = gridDim.y * 128;
    int row0 = blockIdx.x * 128, col0 = blockIdx.y * 128;
    int tid = threadIdx.x;
    int w = tid >> 6, lane = tid & 63;
    int l15 = lane & 15, quad = lane >> 4;

    const unsigned short* ga0 = A  + (size_t)(row0 + w * 32 + (lane >> 2)) * K + (lane & 3) * 8;
    const unsigned short* ga1 = ga0 + 16 * (size_t)K;
    const unsigned short* gw0 = Wt + (size_t)(col0 + w * 32 + (lane >> 2)) * K + (lane & 3) * 8;
    const unsigned short* gw1 = gw0 + 16 * (size_t)K;
    unsigned short* la0 = As + (w * 32) * 32;
    unsigned short* la1 = As + (w * 32 + 16) * 32;
    unsigned short* lw0 = Ws + (w * 32) * 32;
    unsigned short* lw1 = Ws + (w * 32 + 16) * 32;

    int wm = (w & 1) * 64, wn = (w >> 1) * 64;
    const unsigned short* Afr = As + (size_t)(wm + l15) * 32 + quad * 8;
    const unsigned short* Wfr = Ws + (size_t)(wn + l15) * 32 + quad * 8;

    f32x4 acc[4][4] = {};

    for (int k0 = 0; k0 < K; k0 += 32) {
        gld16(ga0 + k0, la0);
        gld16(ga1 + k0, la1);
        gld16(gw0 + k0, lw0);
        gld16(gw1 + k0, lw1);
        __syncthreads();
        bf16x8 af[4], wf[4];
#pragma unroll
        for (int i = 0; i < 4; i++) af[i] = *(const bf16x8*)(Afr + i * 16 * 32);
#pragma unroll
        for (int j = 0; j < 4; j++) wf[j] = *(const bf16x8*)(Wfr + j * 16 * 32);
#pragma unroll
        for (int i = 0; i < 4; i++)
#pragma unroll
            for (int j = 0; j < 4; j++)
                acc[i][j] = __builtin_amdgcn_mfma_f32_16x16x32_bf16(af[i], wf[j], acc[i][j], 0, 0, 0);
        __syncthreads();
    }

#pragma unroll
    for (int i = 0; i < 4; i++) {
        int r = row0 + wm + i * 16 + quad * 4;
#pragma unroll
        for (int j = 0; j < 4; j++) {
            int cc = col0 + wn + j * 16 + l15;
            unsigned short* cp = C + (size_t)r * N + cc;
#pragma unroll
            for (int reg = 0; reg < 4; reg++)
                cp[(size_t)reg * N] = f2bf(acc[i][j][reg]);
        }
    }

    float* red = (float*)As;
    float sj[4], qj[4];
#pragma unroll
    for (int j = 0; j < 4; j++) {
        float s = 0.f, q = 0.f;
#pragma unroll
        for (int i = 0; i < 4; i++)
#pragma unroll
            for (int reg = 0; reg < 4; reg++) {
                float v = acc[i][j][reg];
                s += v; q += v * v;
            }
        s += __shfl_down(s, 32, 64); s += __shfl_down(s, 16, 64);
        q += __shfl_down(q, 32, 64); q += __shfl_down(q, 16, 64);
        sj[j] = s; qj[j] = q;
    }
    if (lane < 16) {
#pragma unroll
        for (int j = 0; j < 4; j++) {
            int cib = wn + j * 16 + lane;
            red[cib * 2 + (w & 1)] = sj[j];
            red[256 + cib * 2 + (w & 1)] = qj[j];
        }
    }
    __syncthreads();
    if (tid < 128) {
        float s = red[tid * 2] + red[tid * 2 + 1];
        float q = red[256 + tid * 2] + red[256 + tid * 2 + 1];
        size_t row = (size_t)z * gridDim.x + blockIdx.x;
        psum[row * N + col0 + tid] = s;
        psq[row * N + col0 + tid] = q;
    }
}

// -------------------- expert BN+swish + gate mix -> mix bf16 [t][b][d] --------------------
// grid B/2, block 256: sub-row = tid>>7 (2 batch rows/block), 4 d per thread, ushort4 I/O
__global__ __launch_bounds__(256) void k_mix(const unsigned short* __restrict__ eh,
                                             const float* __restrict__ scale,
                                             const float* __restrict__ shift,
                                             const float* __restrict__ gates,
                                             unsigned short* __restrict__ mix) {
    __shared__ float scl[E_ * D_], shl[E_ * D_];
    __shared__ float gl[2][2][8];
    int tid = threadIdx.x;
#pragma unroll
    for (int i = 0; i < 4; i++) {
        int li = tid + i * 256;
        ((float4*)scl)[li] = ((const float4*)scale)[li];
        ((float4*)shl)[li] = ((const float4*)shift)[li];
    }
    if (tid < 32) {
        int sub = tid >> 4, t = (tid >> 3) & 1, e = tid & 7;
        gl[sub][t][e] = gates[(size_t)t * (B_ * E_) + (size_t)(blockIdx.x * 2 + sub) * E_ + e];
    }
    __syncthreads();
    int sub = tid >> 7;
    int b = blockIdx.x * 2 + sub;
    int d0 = (tid & 127) * 4;
    float a0[4] = {0.f, 0.f, 0.f, 0.f}, a1[4] = {0.f, 0.f, 0.f, 0.f};
#pragma unroll
    for (int e = 0; e < E_; e++) {
        ushort4 u = *(const ushort4*)&eh[(size_t)b * (E_ * D_) + e * D_ + d0];
        float4 sc4 = *(const float4*)&scl[e * D_ + d0];
        float4 sh4 = *(const float4*)&shl[e * D_ + d0];
        float g0 = gl[sub][0][e], g1 = gl[sub][1][e];
        unsigned short uu[4] = { u.x, u.y, u.z, u.w };
        float scv[4] = { sc4.x, sc4.y, sc4.z, sc4.w };
        float shv[4] = { sh4.x, sh4.y, sh4.z, sh4.w };
#pragma unroll
        for (int l = 0; l < 4; l++) {
            float sw = swishf(scv[l] * bf2f(uu[l]) + shv[l]);
            a0[l] += g0 * sw;
            a1[l] += g1 * sw;
        }
    }
    unsigned short o0[4], o1[4];
#pragma unroll
    for (int l = 0; l < 4; l++) { o0[l] = f2bf(a0[l]); o1[l] = f2bf(a1[l]); }
    *(ushort4*)&mix[(size_t)b * D_ + d0] = *(ushort4*)o0;
    *(ushort4*)&mix[(size_t)(B_ * D_) + (size_t)b * D_ + d0] = *(ushort4*)o1;
}

// -------------------- task BN+swish + final heads, 8 batch rows per block --------------------
__global__ __launch_bounds__(256) void k_final(const unsigned short* __restrict__ th,
                                               const float* __restrict__ scale,
                                               const float* __restrict__ shift,
                                               const float* __restrict__ fwa,
                                               const float* __restrict__ fba,
                                               const float* __restrict__ fwb,
                                               const float* __restrict__ fbb,
                                               float* __restrict__ out) {
    __shared__ float t0[8][D_], t1[8][D_];
    __shared__ float pb[64];
    int tid = threadIdx.x;
    int b0 = blockIdx.x * 8;
#pragma unroll
    for (int t = 0; t < 2; t++) {
#pragma unroll
        for (int i = 0; i < 4; i++) {
            int li = tid + i * 256;
            int row = li >> 7, d = (li & 127) * 4;
            ushort4 u = *(const ushort4*)&th[((size_t)t * B_ + b0 + row) * D_ + d];
            unsigned short uu[4] = { u.x, u.y, u.z, u.w };
            float* dst = t ? &t1[row][d] : &t0[row][d];
#pragma unroll
            for (int l = 0; l < 4; l++)
                dst[l] = swishf(scale[t * D_ + d + l] * bf2f(uu[l]) + shift[t * D_ + d + l]);
        }
    }
    __syncthreads();
    // task a: 8 rows x 32 cols
    {
        int row = tid >> 5, col = tid & 31;
        float acc = fba[col];
        for (int d = 0; d < D_; d++) acc += t0[row][d] * fwa[d * 32 + col];
        out[(size_t)(b0 + row) * OUTW + col] = acc;
    }
    // task b: 8 rows x 2 cols, 4-way split over d
    if (tid < 64) {
        int row = tid >> 3, colb = (tid >> 2) & 1, part = tid & 3;
        float a = 0.f;
        for (int d = part * 128; d < part * 128 + 128; d++) a += t1[row][d] * fwb[d * 2 + colb];
        pb[tid] = a;
    }
    __syncthreads();
    if (tid < 16) {
        int row = tid >> 1, colb = tid & 1;
        int base = row * 8 + colb * 4;
        float a = fbb[colb] + pb[base] + pb[base + 1] + pb[base + 2] + pb[base + 3];
        out[(size_t)(b0 + row) * OUTW + 32 + colb] = a;
    }
}

extern "C" void kernel_launch(void* const* d_in, const int* in_sizes, int n_in,
                              void* d_out, int out_size, void* d_ws, size_t ws_size,
                              hipStream_t stream) {
    const float* x        = (const float*)d_in[0];
    const float* w0       = (const float*)d_in[1];
    const float* b0       = (const float*)d_in[2];
    const float* bn0_g    = (const float*)d_in[3];
    const float* bn0_b    = (const float*)d_in[4];
    const float* gate_w   = (const float*)d_in[5];
    const float* gate_b   = (const float*)d_in[6];
    const float* exp_w    = (const float*)d_in[7];
    const float* exp_bn_g = (const float*)d_in[8];
    const float* exp_bn_b = (const float*)d_in[9];
    const float* task_w   = (const float*)d_in[10];
    const float* task_bn_g= (const float*)d_in[11];
    const float* task_bn_b= (const float*)d_in[12];
    const float* fwa      = (const float*)d_in[13];
    const float* fba      = (const float*)d_in[14];
    const float* fwb      = (const float*)d_in[15];
    const float* fbb      = (const float*)d_in[16];
    float* out = (float*)d_out;

    // workspace (float units). Aliases (disjoint lifetimes):
    //   thbf <- ehbf region (ehbf dead after k_mix)
    //   mixbf <- h0raw region (h0raw dead after k_bnswish_gates)
    float* ws = (float*)d_ws;
    unsigned short* ehbf  = (unsigned short*)ws;              // B*E*D u16 (16,777,216 f)
    unsigned short* h0raw = (unsigned short*)(ws + 16777216); // B*F u16 (4,194,304 f)
    unsigned short* thbf  = ehbf;                             // T*B*D u16 (alias)
    unsigned short* mixbf = h0raw;                            // T*B*D u16 (alias)
    unsigned short* h0bf  = (unsigned short*)(ws + 20971520); // B*F u16 (4,194,304 f)
    unsigned short* wtE   = (unsigned short*)(ws + 25165824); // E*D*F u16 (2,097,152 f)
    unsigned short* twt   = (unsigned short*)(ws + 27262976); // T*D*D u16 (262,144 f)
    float* gates = ws + 27525120;                             // 131,072 f
    float* sc0   = ws + 27656192;
    float* sh0   = sc0 + 1024;
    float* scE   = sh0 + 1024;
    float* shE   = scE + 4096;
    float* scT   = shE + 4096;
    float* shT   = scT + 1024;
    float* psum  = shT + 1024;                                // 262,144 f
    float* psq   = psum + 262144;                             // 262,144 f
    // total ~= 113 MB

    // 0) weight transpose-converts (bf16, K-contiguous rows)
    k_wt<<<dim3(32, 16, 8), 256, 0, stream>>>(exp_w, wtE, F_, D_);   // [E][F][D] -> [E*D][F]
    k_wt<<<dim3(16, 16, 2), 256, 0, stream>>>(task_w, twt, D_, D_);  // [T][D][D] -> [T][D][D]^T
    // 1) split linear (bf16 MFMA) -> h0raw bf16 + fused BN0 partial stats
    k_split<<<dim3(64, 16), 256, 0, stream>>>(x, w0, b0, h0raw, psum, psq);
    k_stats_b<<<dim3(16, 1, 1), 64, 0, stream>>>(psum, psq, F_, 64, bn0_g, bn0_b, 0ull, sc0, sh0, 0ull);
    // 2) BN0 apply + swish -> h0bf + gate softmax
    k_bnswish_gates<<<dim3(B_), 256, 0, stream>>>(h0raw, sc0, sh0, gate_w, gate_b, h0bf, gates);
    // 3) expert GEMM (bf16 MFMA) -> ehbf + fused expert-BN partial stats
    k_gemm_bf16<<<dim3(64, 32, 1), 256, 0, stream>>>(h0bf, 0ull, wtE, 0ull, ehbf, 0ull, F_, psum, psq);
    k_stats_b<<<dim3(64, 1, 1), 64, 0, stream>>>(psum, psq, E_ * D_, 64, exp_bn_g, exp_bn_b, 0ull, scE, shE, 0ull);
    // 4) expert BN apply + swish + gate mix -> mixbf (bf16)
    k_mix<<<dim3(B_ / 2), 256, 0, stream>>>(ehbf, scE, shE, gates, mixbf);
    // 5) task GEMM (bf16 MFMA) -> thbf + fused task-BN partial stats
    k_gemm_bf16<<<dim3(64, 4, 2), 256, 0, stream>>>(mixbf, (unsigned long long)(B_ * D_),
                                                    twt, (unsigned long long)(D_ * D_),
                                                    thbf, (unsigned long long)(B_ * D_), D_,
                                                    psum, psq);
    k_stats_b<<<dim3(8, 1, 2), 64, 0, stream>>>(psum, psq, D_, 64, task_bn_g, task_bn_b, 512ull, scT, shT, 512ull);
    // 6) task BN apply + swish + final heads -> out [B, 34]
    k_final<<<dim3(B_ / 8), 256, 0, stream>>>(thbf, scT, shT, fwa, fba, fwb, fbb, out);
}